// Round 6
// baseline (324.974 us; speedup 1.0000x reference)
//
#include <hip/hip_runtime.h>

typedef unsigned short u16;
typedef unsigned int u32;
typedef __attribute__((ext_vector_type(4))) float f32x4;
typedef __attribute__((ext_vector_type(16))) float f32x16;
typedef __attribute__((ext_vector_type(8))) short bf16x8;
typedef __attribute__((ext_vector_type(4))) short bf16x4;
typedef __attribute__((ext_vector_type(4))) u16 u16x4;
typedef __attribute__((ext_vector_type(2))) u32 u32x2;
typedef __attribute__((ext_vector_type(4))) u32 u32x4;

#define N_NODES 16384
#define N_EDGES 8192
#define FK_SCALE 0.17677669529663687f
#define LOG2E 1.4426950408889634f
#define C1EXP (FK_SCALE * LOG2E)

typedef const u32 __attribute__((address_space(1))) gu32;
typedef u32 __attribute__((address_space(3))) lu32;

__device__ __forceinline__ void gl_lds16(const void* g, void* l) {
  __builtin_amdgcn_global_load_lds((gu32*)g, (lu32*)l, 16, 0, 0);
}

__device__ __forceinline__ float b2f(u16 u) {
  return __builtin_bit_cast(float, (u32)u << 16);
}
__device__ __forceinline__ u16 f2b(float f) {
  u32 u = __builtin_bit_cast(u32, f);
  u += 0x7fffu + ((u >> 16) & 1u);
  return (u16)(u >> 16);
}

__device__ __forceinline__ u32 cvtpk(float a, float b) {
  u32 r;
  asm("v_cvt_pk_bf16_f32 %0, %1, %2" : "=v"(r) : "v"(a), "v"(b));
  return r;
}

// by-value permlane32 swap: returns {new_x, new_y} = swap(low32(x) <-> high32(y))
__device__ __forceinline__ u32x2 swap32v(u32 x, u32 y) {
#if __has_builtin(__builtin_amdgcn_permlane32_swap)
  auto r = __builtin_amdgcn_permlane32_swap(x, y, false, false);
  u32x2 out = {(u32)r[0], (u32)r[1]};
  return out;
#else
  u32 px = __shfl_xor(x, 32, 64), py = __shfl_xor(y, 32, 64);
  bool hi = (threadIdx.x & 32) != 0;
  u32x2 out = {hi ? x : py, hi ? px : y};
  return out;
#endif
}

// ---------------- fused: X->bf16 + e_ids histogram (blocks 0..4095)
//                  + W transpose/cvt + bias pack (blocks 4096..4159) ----------------
__global__ __launch_bounds__(256) void k_prep(const float* __restrict__ X,
                                              const int* __restrict__ e_ids,
                                              u16* __restrict__ Xb,
                                              int* __restrict__ hist,
                                              const float* __restrict__ Wq,
                                              const float* __restrict__ Wk,
                                              const float* __restrict__ Wv,
                                              const float* __restrict__ Wke,
                                              const float* __restrict__ bq,
                                              const float* __restrict__ bk,
                                              const float* __restrict__ bv,
                                              const float* __restrict__ bke,
                                              u16* __restrict__ Wt,
                                              float* __restrict__ bcat) {
  __shared__ float tile[64][65];
  int b = blockIdx.x;
  int tid = threadIdx.x;
  if (b < 4096) {
    int i = b * 256 + tid;
    f32x4 v = *(const f32x4*)(X + (size_t)i * 4);
    u16x4 r;
    r.x = f2b(v.x); r.y = f2b(v.y); r.z = f2b(v.z); r.w = f2b(v.w);
    *(u16x4*)(Xb + (size_t)i * 4) = r;
    if (tid < 64) atomicAdd(&hist[e_ids[b * 64 + tid]], 1);
    return;
  }
  int local = b - 4096;
  int w = local >> 4, rem = local & 15;
  int k0 = (rem >> 2) * 64, n0 = (rem & 3) * 64;
  const float* W = (w == 0) ? Wq : (w == 1) ? Wk : (w == 2) ? Wv : Wke;
  if (rem == 0) {
    const float* bb = (w == 0) ? bq : (w == 1) ? bk : (w == 2) ? bv : bke;
    bcat[w * 256 + tid] = bb[tid];
  }
#pragma unroll
  for (int i = 0; i < 16; i++) {
    int idx = i * 256 + tid;
    int kr = idx >> 6, nc = idx & 63;
    tile[nc][kr] = W[(k0 + kr) * 256 + n0 + nc];
  }
  __syncthreads();
#pragma unroll
  for (int i = 0; i < 16; i++) {
    int idx = i * 256 + tid;
    int nr = idx >> 6, kc = idx & 63;
    Wt[w * 65536 + (n0 + nr) * 256 + k0 + kc] = f2b(tile[nr][kc]);
  }
}

// ---------------- exclusive scan (1 block) ----------------
__global__ __launch_bounds__(256) void k_scan(const int* __restrict__ hist,
                                              int* __restrict__ eoff,
                                              int* __restrict__ cur) {
  __shared__ int ts[256];
  int t = threadIdx.x;
  int base = t * 32;
  int vals[32];
  int s = 0;
#pragma unroll
  for (int i = 0; i < 32; i++) { vals[i] = hist[base + i]; s += vals[i]; }
  ts[t] = s;
  __syncthreads();
  for (int off = 1; off < 256; off <<= 1) {
    int v = (t >= off) ? ts[t - off] : 0;
    __syncthreads();
    ts[t] += v;
    __syncthreads();
  }
  int ex = ts[t] - s;
#pragma unroll
  for (int i = 0; i < 32; i++) {
    eoff[base + i] = ex;
    cur[base + i] = ex;
    ex += vals[i];
  }
  if (t == 255) eoff[8192] = ex;
}

// ---------------- permute ----------------
__global__ __launch_bounds__(256) void k_perm(const int* __restrict__ v_ids,
                                              const int* __restrict__ e_ids,
                                              int* __restrict__ cur,
                                              int* __restrict__ perm) {
  int base = blockIdx.x * 1024 + threadIdx.x;
#pragma unroll
  for (int k = 0; k < 4; k++) {
    int i = base + k * 256;
    int e = e_ids[i];
    int v = v_ids[i];
    int pos = atomicAdd(&cur[e], 1);
    perm[pos] = v;
  }
}

// ---------------- fused launch: gemm-QKV (blocks 0..767) + gather (768..2815) ----------------
__global__ __launch_bounds__(256) void k_gg(const u16* __restrict__ Xb,
                                            const int* __restrict__ perm,
                                            const int* __restrict__ eoff,
                                            u16* __restrict__ Xe,
                                            u16* __restrict__ XeTc,
                                            const u16* __restrict__ Wt,
                                            const float* __restrict__ bcat,
                                            u16* __restrict__ QKV) {
  __shared__ u16 As[128 * 64];
  __shared__ u16 Bs[128 * 64];
  int b = blockIdx.x;
  int tid = threadIdx.x;
  int wave = tid >> 6, lane = tid & 63;
  if (b < 768) {
    // ---- 128x128 swizzled GEMM: QKV = Xb @ Wt^T + bias ----
    int quad = lane >> 4, l16 = lane & 15;
    int wm = wave >> 1, wn = wave & 1;
    int mtile = (b & 127) * 128, ntile = (b >> 7) * 128;
    const u16* Ap = Xb + (size_t)mtile * 256;
    const u16* Bp = Wt + (size_t)ntile * 256;
    f32x4 acc[4][4];
#pragma unroll
    for (int am = 0; am < 4; am++)
#pragma unroll
      for (int bn = 0; bn < 4; bn++) acc[am][bn] = (f32x4){0.f, 0.f, 0.f, 0.f};
    for (int ks = 0; ks < 4; ks++) {
      __syncthreads();
#pragma unroll
      for (int i = 0; i < 4; i++) {
        int s = i * 256 + tid;
        int r = s >> 3, c = s & 7;
        gl_lds16(Ap + r * 256 + ks * 64 + ((c ^ (r & 7)) << 3), As + s * 8);
      }
#pragma unroll
      for (int i = 0; i < 4; i++) {
        int s = i * 256 + tid;
        int r = s >> 3, c = s & 7;
        gl_lds16(Bp + r * 256 + ks * 64 + ((c ^ (r & 7)) << 3), Bs + s * 8);
      }
      __syncthreads();
#pragma unroll
      for (int kc = 0; kc < 2; kc++) {
        bf16x8 a[4], bb[4];
        int cc = kc * 4 + quad;
#pragma unroll
        for (int am = 0; am < 4; am++) {
          int rl = wm * 64 + am * 16 + l16;
          a[am] = *(const bf16x8*)(As + rl * 64 + ((cc ^ (rl & 7)) << 3));
        }
#pragma unroll
        for (int bn = 0; bn < 4; bn++) {
          int rl = wn * 64 + bn * 16 + l16;
          bb[bn] = *(const bf16x8*)(Bs + rl * 64 + ((cc ^ (rl & 7)) << 3));
        }
#pragma unroll
        for (int am = 0; am < 4; am++)
#pragma unroll
          for (int bn = 0; bn < 4; bn++)
            acc[am][bn] = __builtin_amdgcn_mfma_f32_16x16x32_bf16(a[am], bb[bn], acc[am][bn], 0, 0, 0);
      }
    }
#pragma unroll
    for (int am = 0; am < 4; am++)
#pragma unroll
      for (int bn = 0; bn < 4; bn++)
#pragma unroll
        for (int r = 0; r < 4; r++) {
          int row = mtile + wm * 64 + am * 16 + quad * 4 + r;
          int col = ntile + wn * 64 + bn * 16 + l16;
          QKV[(size_t)row * 768 + col] = f2b(acc[am][bn][r] + bcat[col]);
        }
    return;
  }
  // ---- gather: wave-per-edge, perm indices preloaded + shfl-broadcast ----
  int e = (b - 768) * 4 + wave;
  int start = eoff[e], end = eoff[e + 1];
  int cnt = end - start;
  int pidx = 0;
  if (lane < cnt) pidx = perm[start + lane];
  f32x4 acc = {0.f, 0.f, 0.f, 0.f};
  int n1 = cnt < 64 ? cnt : 64;
  for (int j = 0; j < n1; j++) {
    int v = __shfl(pidx, j, 64);
    bf16x4 x = *(const bf16x4*)(Xb + (size_t)v * 256 + lane * 4);
#pragma unroll
    for (int c = 0; c < 4; c++) acc[c] += b2f((u16)x[c]);
  }
  for (int j = start + 64; j < end; j++) {
    int v = perm[j];
    bf16x4 x = *(const bf16x4*)(Xb + (size_t)v * 256 + lane * 4);
#pragma unroll
    for (int c = 0; c < 4; c++) acc[c] += b2f((u16)x[c]);
  }
  float inv = 1.0f / fmaxf((float)cnt, 1.0f);
  u16x4 r;
  r.x = f2b(acc.x * inv); r.y = f2b(acc.y * inv);
  r.z = f2b(acc.z * inv); r.w = f2b(acc.w * inv);
  *(u16x4*)(Xe + (size_t)e * 256 + lane * 4) = r;
  size_t tb = (size_t)(e >> 3) * 2048 + (e & 7);
  XeTc[tb + (lane * 4 + 0) * 8] = r.x;
  XeTc[tb + (lane * 4 + 1) * 8] = r.y;
  XeTc[tb + (lane * 4 + 2) * 8] = r.z;
  XeTc[tb + (lane * 4 + 3) * 8] = r.w;
}

// ---------------- 128x128 swizzled GEMM for Ke, chunk-major out ----------------
__global__ __launch_bounds__(256) void k_gemmke(const u16* __restrict__ A,
                                                const u16* __restrict__ Wt,
                                                const float* __restrict__ bias,
                                                u16* __restrict__ KebT) {
  __shared__ u16 As[128 * 64];
  __shared__ u16 Bs[128 * 64];
  int tid = threadIdx.x;
  int wave = tid >> 6, lane = tid & 63;
  int quad = lane >> 4, l16 = lane & 15;
  int wm = wave >> 1, wn = wave & 1;
  int mtile = blockIdx.x * 128, ntile = blockIdx.y * 128;
  const u16* Ap = A + (size_t)mtile * 256;
  const u16* Bp = Wt + (size_t)ntile * 256;
  f32x4 acc[4][4];
#pragma unroll
  for (int am = 0; am < 4; am++)
#pragma unroll
    for (int bn = 0; bn < 4; bn++) acc[am][bn] = (f32x4){0.f, 0.f, 0.f, 0.f};
  for (int ks = 0; ks < 4; ks++) {
    __syncthreads();
#pragma unroll
    for (int i = 0; i < 4; i++) {
      int s = i * 256 + tid;
      int r = s >> 3, c = s & 7;
      gl_lds16(Ap + r * 256 + ks * 64 + ((c ^ (r & 7)) << 3), As + s * 8);
    }
#pragma unroll
    for (int i = 0; i < 4; i++) {
      int s = i * 256 + tid;
      int r = s >> 3, c = s & 7;
      gl_lds16(Bp + r * 256 + ks * 64 + ((c ^ (r & 7)) << 3), Bs + s * 8);
    }
    __syncthreads();
#pragma unroll
    for (int kc = 0; kc < 2; kc++) {
      bf16x8 a[4], b[4];
      int cc = kc * 4 + quad;
#pragma unroll
      for (int am = 0; am < 4; am++) {
        int rl = wm * 64 + am * 16 + l16;
        a[am] = *(const bf16x8*)(As + rl * 64 + ((cc ^ (rl & 7)) << 3));
      }
#pragma unroll
      for (int bn = 0; bn < 4; bn++) {
        int rl = wn * 64 + bn * 16 + l16;
        b[bn] = *(const bf16x8*)(Bs + rl * 64 + ((cc ^ (rl & 7)) << 3));
      }
#pragma unroll
      for (int am = 0; am < 4; am++)
#pragma unroll
        for (int bn = 0; bn < 4; bn++)
          acc[am][bn] = __builtin_amdgcn_mfma_f32_16x16x32_bf16(a[am], b[bn], acc[am][bn], 0, 0, 0);
    }
  }
#pragma unroll
  for (int am = 0; am < 4; am++)
#pragma unroll
    for (int bn = 0; bn < 4; bn++)
#pragma unroll
      for (int r = 0; r < 4; r++) {
        int row = mtile + wm * 64 + am * 16 + quad * 4 + r;
        int col = ntile + wn * 64 + bn * 16 + l16;
        KebT[(size_t)(col >> 3) * 65536 + row * 8 + (col & 7)] = f2b(acc[am][bn][r] + bias[col]);
      }
}

// ---------------- flash staging helpers: 32-key tiles (16 KB each) ----------------
__device__ __forceinline__ void stage_k(const u16* __restrict__ KebT, u16* KeL,
                                        int kbase, int tid) {
#pragma unroll
  for (int i = 0; i < 4; i++) {
    int s = i * 256 + tid;
    int c = s >> 5, r = s & 31;
    gl_lds16(KebT + ((size_t)c * 8192 + kbase + r) * 8, KeL + s * 8);
  }
}
__device__ __forceinline__ void stage_v(const u16* __restrict__ XeTc, u16* VLT,
                                        int ktg, int tid) {
  int kb8 = ktg * 4;
#pragma unroll
  for (int i = 0; i < 4; i++) {
    int s = i * 256 + tid;
    int kc = s >> 8, ch = s & 255;
    gl_lds16(XeTc + ((size_t)(kb8 + kc) * 256 + ch) * 8, VLT + s * 8);
  }
}

// ---------------- flash partial, 32x32x16, wave-independent q-tiles, 32-key iters ----
// 512 blocks = 128 q-tiles (128 rows) x 4 key-splits; 4 waves each own 32 q-rows;
// 64 iters of 32 keys. DOUBLE-BUFFERED LDS (2 x 32 KB), ONE barrier per iter:
// barrier -> issue stage(t+1) into buf^1 -> QK/exp/PV from buf. Staged loads get the
// full compute phase (~2500 cyc) to land vs half-iter before; 64 barrier drains vs 128.
// x2-unrolled loop keeps buffer selection compile-time (no VGPR cost; ds offsets fold
// into the 16-bit immediate, max 65024 B). Register budget unchanged from round 5
// (VGPR 124 + AGPR 128 <= 256 at 2 blocks/CU -> no spill).
__global__ __launch_bounds__(256, 2) void k_flash(const u16* __restrict__ QKV,
                                                  const u16* __restrict__ KebT,
                                                  const u16* __restrict__ XeTc,
                                                  u16* __restrict__ Op,
                                                  float* __restrict__ Lv) {
  extern __shared__ u16 sm[];
  // buf B at sm + B*16384 (u16 units): KeL = +0 (16 KB), VLT = +8192 (16 KB)
  int tid = threadIdx.x;
  int wave = tid >> 6, lane = tid & 63;
  int l31 = lane & 31, half = lane >> 5;
  int qt = blockIdx.x & 127;
  int split = blockIdx.x >> 7;
  int rowq = qt * 128 + wave * 32 + l31;

  bf16x8 qf[16];
#pragma unroll
  for (int ks = 0; ks < 16; ks++)
    qf[ks] = *(const bf16x8*)(QKV + (size_t)rowq * 768 + ks * 16 + half * 8);

  f32x16 o[8];
#pragma unroll
  for (int i = 0; i < 8; i++)
#pragma unroll
    for (int r = 0; r < 16; r++) o[i][r] = 0.f;
  float lsum = 0.f;

  // prologue: stage tile 0 into buf0
  stage_k(KebT, sm, split * 2048, tid);
  stage_v(XeTc, sm + 8192, split * 64, tid);

#define FLASH_STEP(RB, T)                                                          \
  {                                                                                \
    __syncthreads(); /* buf[RB] resident; all reads of buf[RB^1] done */           \
    int ktg = split * 64 + (T);                                                    \
    if ((T) + 1 < 64) {                                                            \
      stage_k(KebT, sm + ((RB) ^ 1) * 16384, (ktg + 1) * 32, tid);                 \
      stage_v(XeTc, sm + ((RB) ^ 1) * 16384 + 8192, ktg + 1, tid);                 \
    }                                                                              \
    const u16* kp = sm + (RB) * 16384 + half * 256 + l31 * 8;                      \
    const u16* vp = sm + (RB) * 16384 + 8192 + half * 2048 + l31 * 8;              \
    f32x16 s0;                                                                     \
    _Pragma("unroll") for (int r = 0; r < 16; r++) s0[r] = 0.f;                    \
    __builtin_amdgcn_s_setprio(1);                                                 \
    _Pragma("unroll") for (int ks = 0; ks < 16; ks++) {                            \
      bf16x8 ka = *(const bf16x8*)(kp + ks * 512);                                 \
      s0 = __builtin_amdgcn_mfma_f32_32x32x16_bf16(ka, qf[ks], s0, 0, 0, 0);       \
    }                                                                              \
    __builtin_amdgcn_s_setprio(0);                                                 \
    u32 w[8];                                                                      \
    _Pragma("unroll") for (int i = 0; i < 8; i++) {                                \
      float e0 = __builtin_amdgcn_exp2f(s0[2 * i] * C1EXP);                        \
      float e1 = __builtin_amdgcn_exp2f(s0[2 * i + 1] * C1EXP);                    \
      lsum += e0 + e1;                                                             \
      w[i] = cvtpk(e0, e1);                                                        \
    }                                                                              \
    {                                                                              \
      u32x2 r;                                                                     \
      r = swap32v(w[2], w[0]); w[2] = r.x; w[0] = r.y;                             \
      r = swap32v(w[3], w[1]); w[3] = r.x; w[1] = r.y;                             \
      r = swap32v(w[6], w[4]); w[6] = r.x; w[4] = r.y;                             \
      r = swap32v(w[7], w[5]); w[7] = r.x; w[5] = r.y;                             \
    }                                                                              \
    u32x4 p0v = {w[0], w[1], w[2], w[3]};                                          \
    u32x4 p1v = {w[4], w[5], w[6], w[7]};                                          \
    bf16x8 pf0 = __builtin_bit_cast(bf16x8, p0v);                                  \
    bf16x8 pf1 = __builtin_bit_cast(bf16x8, p1v);                                  \
    __builtin_amdgcn_s_setprio(1);                                                 \
    _Pragma("unroll") for (int ct = 0; ct < 8; ct++) {                             \
      const u16* vpc = vp + ct * 256;                                              \
      o[ct] = __builtin_amdgcn_mfma_f32_32x32x16_bf16(pf0, *(const bf16x8*)(vpc), o[ct], 0, 0, 0); \
      o[ct] = __builtin_amdgcn_mfma_f32_32x32x16_bf16(pf1, *(const bf16x8*)(vpc + 4096), o[ct], 0, 0, 0); \
    }                                                                              \
    __builtin_amdgcn_s_setprio(0);                                                 \
  }

  for (int t2 = 0; t2 < 64; t2 += 2) {
    FLASH_STEP(0, t2);
    FLASH_STEP(1, t2 + 1);
  }
#undef FLASH_STEP

  // per-lane scalar holds the partial row-sum for q = l31 over this lane's keys;
  // the other half-lane holds the complementary keys.
  lsum += __shfl_xor(lsum, 32, 64);
  if (lane < 32) Lv[split * N_NODES + qt * 128 + wave * 32 + l31] = lsum;

  size_t obase = (size_t)split * N_NODES * 256;
#pragma unroll
  for (int ct = 0; ct < 8; ct++)
#pragma unroll
    for (int reg = 0; reg < 16; reg++) {
      int row = qt * 128 + wave * 32 + (reg & 3) + 8 * (reg >> 2) + 4 * half;
      int col = ct * 32 + l31;
      Op[obase + (size_t)row * 256 + col] = f2b(o[ct][reg]);
    }
}

// ---------------- fused: node 8x8 head attention + split combine + ReLU ----------------
__global__ __launch_bounds__(256) void k_comb(const u16* __restrict__ QKV,
                                              const u16* __restrict__ Op,
                                              const float* __restrict__ Lv,
                                              float* __restrict__ out) {
  int idx = blockIdx.x * 256 + threadIdx.x;
  int n = idx >> 6, lane = idx & 63;
  int h = lane >> 3, g = lane & 7;
  const u16* base = QKV + n * 768;
  const bf16x8* qp = (const bf16x8*)(base + h * 32);
  const bf16x8* kp = (const bf16x8*)(base + 256 + g * 32);
  float s = 0.f;
#pragma unroll
  for (int t = 0; t < 4; t++) {
    bf16x8 qv = qp[t], kv = kp[t];
#pragma unroll
    for (int j = 0; j < 8; j++) s += b2f((u16)qv[j]) * b2f((u16)kv[j]);
  }
  s *= FK_SCALE;
  float mx = s;
#pragma unroll
  for (int off = 1; off < 8; off <<= 1) mx = fmaxf(mx, __shfl_xor(mx, off, 64));
  float p = __builtin_amdgcn_exp2f((s - mx) * LOG2E);
  float lsum = p;
#pragma unroll
  for (int off = 1; off < 8; off <<= 1) lsum += __shfl_xor(lsum, off, 64);
  float attn = p / lsum;
  float a4[4] = {0.f, 0.f, 0.f, 0.f};
#pragma unroll
  for (int g2 = 0; g2 < 8; g2++) {
    float a = __shfl(attn, (lane & 56) | g2, 64);
    bf16x4 vv = *(const bf16x4*)(base + 512 + g2 * 32 + g * 4);
#pragma unroll
    for (int j = 0; j < 4; j++) a4[j] += a * b2f((u16)vv[j]);
  }
  int c4 = lane * 4;
  float L = 0.f;
#pragma unroll
  for (int sl = 0; sl < 4; sl++) L += Lv[sl * N_NODES + n];
  f32x4 acc = {0.f, 0.f, 0.f, 0.f};
#pragma unroll
  for (int sp = 0; sp < 4; sp++) {
    u16x4 ov = *(const u16x4*)(Op + (size_t)sp * N_NODES * 256 + (size_t)n * 256 + c4);
    acc.x += b2f(ov.x);
    acc.y += b2f(ov.y);
    acc.z += b2f(ov.z);
    acc.w += b2f(ov.w);
  }
  float invL = 1.0f / L;
  f32x4 res;
  res.x = fmaxf(acc.x * invL + a4[0], 0.f);
  res.y = fmaxf(acc.y * invL + a4[1], 0.f);
  res.z = fmaxf(acc.z * invL + a4[2], 0.f);
  res.w = fmaxf(acc.w * invL + a4[3], 0.f);
  *(f32x4*)(out + (size_t)n * 256 + c4) = res;
}

extern "C" void kernel_launch(void* const* d_in, const int* in_sizes, int n_in,
                              void* d_out, int out_size, void* d_ws, size_t ws_size,
                              hipStream_t stream) {
  const float* X = (const float*)d_in[0];
  const int* v_ids = (const int*)d_in[1];
  const int* e_ids = (const int*)d_in[2];
  const float* Wq = (const float*)d_in[3];
  const float* bq = (const float*)d_in[4];
  const float* Wk = (const float*)d_in[5];
  const float* bk = (const float*)d_in[6];
  const float* Wv = (const float*)d_in[7];
  const float* bv = (const float*)d_in[8];
  const float* Wke = (const float*)d_in[9];
  const float* bke = (const float*)d_in[10];
  float* out = (float*)d_out;

  char* ws = (char*)d_ws;
  u16* Xb = (u16*)(ws);                       // 8 MB   [N][256] bf16
  u16* QKV = (u16*)(ws + 8388608);            // 24 MB  [N][768] bf16
  u16* Wt = (u16*)(ws + 33554432);            // 512 KB
  float* bcat = (float*)(ws + 34078720);      // 4 KB
  int* hist = (int*)(ws + 34082816);          // 32 KB
  int* eoff = (int*)(ws + 34115584);          // 36 KB
  int* cur = (int*)(ws + 34152448);           // 32 KB
  int* perm = (int*)(ws + 34185216);          // 1 MB
  u16* Xe = (u16*)(ws + 35233792);            // 4 MB   [E][256]
  u16* XeTc = (u16*)(ws + 39428096);          // 4 MB   [E/8][256][8]
  u16* KebT = (u16*)(ws + 43622400);          // 4 MB   [32][E][8]
  u16* Op = (u16*)(ws + 64593920);            // 32 MB  [4][N][256] bf16
  float* Lv = (float*)(ws + 98148352);        // 256 KB [4][N]

  hipMemsetAsync(hist, 0, 32768, stream);
  k_prep<<<4160, 256, 0, stream>>>(X, e_ids, Xb, hist, Wq, Wk, Wv, Wke,
                                   bq, bk, bv, bke, Wt, bcat);
  k_scan<<<1, 256, 0, stream>>>(hist, eoff, cur);
  k_perm<<<256, 256, 0, stream>>>(v_ids, e_ids, cur, perm);
  k_gg<<<2816, 256, 0, stream>>>(Xb, perm, eoff, Xe, XeTc, Wt, bcat, QKV);
  k_gemmke<<<dim3(64, 2), 256, 0, stream>>>(Xe, Wt + 3 * 65536, bcat + 768, KebT);
  hipFuncSetAttribute((const void*)k_flash, hipFuncAttributeMaxDynamicSharedMemorySize,
                      65536);
  k_flash<<<512, 256, 65536, stream>>>(QKV, KebT, XeTc, Op, Lv);
  k_comb<<<4096, 256, 0, stream>>>(QKV, Op, Lv, out);
}

// Round 7
// 307.447 us; speedup vs baseline: 1.0570x; 1.0570x over previous
//
#include <hip/hip_runtime.h>

typedef unsigned short u16;
typedef unsigned int u32;
typedef __attribute__((ext_vector_type(4))) float f32x4;
typedef __attribute__((ext_vector_type(16))) float f32x16;
typedef __attribute__((ext_vector_type(8))) short bf16x8;
typedef __attribute__((ext_vector_type(4))) short bf16x4;
typedef __attribute__((ext_vector_type(4))) u16 u16x4;
typedef __attribute__((ext_vector_type(2))) u32 u32x2;
typedef __attribute__((ext_vector_type(4))) u32 u32x4;

#define N_NODES 16384
#define N_EDGES 8192
#define FK_SCALE 0.17677669529663687f
#define LOG2E 1.4426950408889634f
#define C1EXP (FK_SCALE * LOG2E)

typedef const u32 __attribute__((address_space(1))) gu32;
typedef u32 __attribute__((address_space(3))) lu32;

__device__ __forceinline__ void gl_lds16(const void* g, void* l) {
  __builtin_amdgcn_global_load_lds((gu32*)g, (lu32*)l, 16, 0, 0);
}

__device__ __forceinline__ float b2f(u16 u) {
  return __builtin_bit_cast(float, (u32)u << 16);
}
__device__ __forceinline__ u16 f2b(float f) {
  u32 u = __builtin_bit_cast(u32, f);
  u += 0x7fffu + ((u >> 16) & 1u);
  return (u16)(u >> 16);
}

__device__ __forceinline__ u32 cvtpk(float a, float b) {
  u32 r;
  asm("v_cvt_pk_bf16_f32 %0, %1, %2" : "=v"(r) : "v"(a), "v"(b));
  return r;
}

// by-value permlane32 swap: returns {new_x, new_y} = swap(low32(x) <-> high32(y))
__device__ __forceinline__ u32x2 swap32v(u32 x, u32 y) {
#if __has_builtin(__builtin_amdgcn_permlane32_swap)
  auto r = __builtin_amdgcn_permlane32_swap(x, y, false, false);
  u32x2 out = {(u32)r[0], (u32)r[1]};
  return out;
#else
  u32 px = __shfl_xor(x, 32, 64), py = __shfl_xor(y, 32, 64);
  bool hi = (threadIdx.x & 32) != 0;
  u32x2 out = {hi ? x : py, hi ? px : y};
  return out;
#endif
}

// ---------------- fused: X->bf16 + e_ids histogram (blocks 0..4095)
//                  + W transpose/cvt + bias pack (blocks 4096..4159) ----------------
__global__ __launch_bounds__(256) void k_prep(const float* __restrict__ X,
                                              const int* __restrict__ e_ids,
                                              u16* __restrict__ Xb,
                                              int* __restrict__ hist,
                                              const float* __restrict__ Wq,
                                              const float* __restrict__ Wk,
                                              const float* __restrict__ Wv,
                                              const float* __restrict__ Wke,
                                              const float* __restrict__ bq,
                                              const float* __restrict__ bk,
                                              const float* __restrict__ bv,
                                              const float* __restrict__ bke,
                                              u16* __restrict__ Wt,
                                              float* __restrict__ bcat) {
  __shared__ float tile[64][65];
  int b = blockIdx.x;
  int tid = threadIdx.x;
  if (b < 4096) {
    int i = b * 256 + tid;
    f32x4 v = *(const f32x4*)(X + (size_t)i * 4);
    u16x4 r;
    r.x = f2b(v.x); r.y = f2b(v.y); r.z = f2b(v.z); r.w = f2b(v.w);
    *(u16x4*)(Xb + (size_t)i * 4) = r;
    if (tid < 64) atomicAdd(&hist[e_ids[b * 64 + tid]], 1);
    return;
  }
  int local = b - 4096;
  int w = local >> 4, rem = local & 15;
  int k0 = (rem >> 2) * 64, n0 = (rem & 3) * 64;
  const float* W = (w == 0) ? Wq : (w == 1) ? Wk : (w == 2) ? Wv : Wke;
  if (rem == 0) {
    const float* bb = (w == 0) ? bq : (w == 1) ? bk : (w == 2) ? bv : bke;
    bcat[w * 256 + tid] = bb[tid];
  }
#pragma unroll
  for (int i = 0; i < 16; i++) {
    int idx = i * 256 + tid;
    int kr = idx >> 6, nc = idx & 63;
    tile[nc][kr] = W[(k0 + kr) * 256 + n0 + nc];
  }
  __syncthreads();
#pragma unroll
  for (int i = 0; i < 16; i++) {
    int idx = i * 256 + tid;
    int nr = idx >> 6, kc = idx & 63;
    Wt[w * 65536 + (n0 + nr) * 256 + k0 + kc] = f2b(tile[nr][kc]);
  }
}

// ---------------- exclusive scan (1 block) ----------------
__global__ __launch_bounds__(256) void k_scan(const int* __restrict__ hist,
                                              int* __restrict__ eoff,
                                              int* __restrict__ cur) {
  __shared__ int ts[256];
  int t = threadIdx.x;
  int base = t * 32;
  int vals[32];
  int s = 0;
#pragma unroll
  for (int i = 0; i < 32; i++) { vals[i] = hist[base + i]; s += vals[i]; }
  ts[t] = s;
  __syncthreads();
  for (int off = 1; off < 256; off <<= 1) {
    int v = (t >= off) ? ts[t - off] : 0;
    __syncthreads();
    ts[t] += v;
    __syncthreads();
  }
  int ex = ts[t] - s;
#pragma unroll
  for (int i = 0; i < 32; i++) {
    eoff[base + i] = ex;
    cur[base + i] = ex;
    ex += vals[i];
  }
  if (t == 255) eoff[8192] = ex;
}

// ---------------- permute ----------------
__global__ __launch_bounds__(256) void k_perm(const int* __restrict__ v_ids,
                                              const int* __restrict__ e_ids,
                                              int* __restrict__ cur,
                                              int* __restrict__ perm) {
  int base = blockIdx.x * 1024 + threadIdx.x;
#pragma unroll
  for (int k = 0; k < 4; k++) {
    int i = base + k * 256;
    int e = e_ids[i];
    int v = v_ids[i];
    int pos = atomicAdd(&cur[e], 1);
    perm[pos] = v;
  }
}

// ---------------- fused launch: gemm-QKV (blocks 0..767) + gather (768..2815) ----------------
__global__ __launch_bounds__(256) void k_gg(const u16* __restrict__ Xb,
                                            const int* __restrict__ perm,
                                            const int* __restrict__ eoff,
                                            u16* __restrict__ Xe,
                                            u16* __restrict__ XeTc,
                                            const u16* __restrict__ Wt,
                                            const float* __restrict__ bcat,
                                            u16* __restrict__ QKV) {
  __shared__ u16 As[128 * 64];
  __shared__ u16 Bs[128 * 64];
  int b = blockIdx.x;
  int tid = threadIdx.x;
  int wave = tid >> 6, lane = tid & 63;
  if (b < 768) {
    // ---- 128x128 swizzled GEMM: QKV = Xb @ Wt^T + bias ----
    int quad = lane >> 4, l16 = lane & 15;
    int wm = wave >> 1, wn = wave & 1;
    int mtile = (b & 127) * 128, ntile = (b >> 7) * 128;
    const u16* Ap = Xb + (size_t)mtile * 256;
    const u16* Bp = Wt + (size_t)ntile * 256;
    f32x4 acc[4][4];
#pragma unroll
    for (int am = 0; am < 4; am++)
#pragma unroll
      for (int bn = 0; bn < 4; bn++) acc[am][bn] = (f32x4){0.f, 0.f, 0.f, 0.f};
    for (int ks = 0; ks < 4; ks++) {
      __syncthreads();
#pragma unroll
      for (int i = 0; i < 4; i++) {
        int s = i * 256 + tid;
        int r = s >> 3, c = s & 7;
        gl_lds16(Ap + r * 256 + ks * 64 + ((c ^ (r & 7)) << 3), As + s * 8);
      }
#pragma unroll
      for (int i = 0; i < 4; i++) {
        int s = i * 256 + tid;
        int r = s >> 3, c = s & 7;
        gl_lds16(Bp + r * 256 + ks * 64 + ((c ^ (r & 7)) << 3), Bs + s * 8);
      }
      __syncthreads();
#pragma unroll
      for (int kc = 0; kc < 2; kc++) {
        bf16x8 a[4], bb[4];
        int cc = kc * 4 + quad;
#pragma unroll
        for (int am = 0; am < 4; am++) {
          int rl = wm * 64 + am * 16 + l16;
          a[am] = *(const bf16x8*)(As + rl * 64 + ((cc ^ (rl & 7)) << 3));
        }
#pragma unroll
        for (int bn = 0; bn < 4; bn++) {
          int rl = wn * 64 + bn * 16 + l16;
          bb[bn] = *(const bf16x8*)(Bs + rl * 64 + ((cc ^ (rl & 7)) << 3));
        }
#pragma unroll
        for (int am = 0; am < 4; am++)
#pragma unroll
          for (int bn = 0; bn < 4; bn++)
            acc[am][bn] = __builtin_amdgcn_mfma_f32_16x16x32_bf16(a[am], bb[bn], acc[am][bn], 0, 0, 0);
      }
    }
#pragma unroll
    for (int am = 0; am < 4; am++)
#pragma unroll
      for (int bn = 0; bn < 4; bn++)
#pragma unroll
        for (int r = 0; r < 4; r++) {
          int row = mtile + wm * 64 + am * 16 + quad * 4 + r;
          int col = ntile + wn * 64 + bn * 16 + l16;
          QKV[(size_t)row * 768 + col] = f2b(acc[am][bn][r] + bcat[col]);
        }
    return;
  }
  // ---- gather: wave-per-edge, perm indices preloaded + shfl-broadcast ----
  int e = (b - 768) * 4 + wave;
  int start = eoff[e], end = eoff[e + 1];
  int cnt = end - start;
  int pidx = 0;
  if (lane < cnt) pidx = perm[start + lane];
  f32x4 acc = {0.f, 0.f, 0.f, 0.f};
  int n1 = cnt < 64 ? cnt : 64;
  for (int j = 0; j < n1; j++) {
    int v = __shfl(pidx, j, 64);
    bf16x4 x = *(const bf16x4*)(Xb + (size_t)v * 256 + lane * 4);
#pragma unroll
    for (int c = 0; c < 4; c++) acc[c] += b2f((u16)x[c]);
  }
  for (int j = start + 64; j < end; j++) {
    int v = perm[j];
    bf16x4 x = *(const bf16x4*)(Xb + (size_t)v * 256 + lane * 4);
#pragma unroll
    for (int c = 0; c < 4; c++) acc[c] += b2f((u16)x[c]);
  }
  float inv = 1.0f / fmaxf((float)cnt, 1.0f);
  u16x4 r;
  r.x = f2b(acc.x * inv); r.y = f2b(acc.y * inv);
  r.z = f2b(acc.z * inv); r.w = f2b(acc.w * inv);
  *(u16x4*)(Xe + (size_t)e * 256 + lane * 4) = r;
  size_t tb = (size_t)(e >> 3) * 2048 + (e & 7);
  XeTc[tb + (lane * 4 + 0) * 8] = r.x;
  XeTc[tb + (lane * 4 + 1) * 8] = r.y;
  XeTc[tb + (lane * 4 + 2) * 8] = r.z;
  XeTc[tb + (lane * 4 + 3) * 8] = r.w;
}

// ---------------- 128x128 swizzled GEMM for Ke, chunk-major out ----------------
// NOTE: output pre-scaled by C1EXP (= FK_SCALE*LOG2E) so k_flash's exp2 needs no mul.
__global__ __launch_bounds__(256) void k_gemmke(const u16* __restrict__ A,
                                                const u16* __restrict__ Wt,
                                                const float* __restrict__ bias,
                                                u16* __restrict__ KebT) {
  __shared__ u16 As[128 * 64];
  __shared__ u16 Bs[128 * 64];
  int tid = threadIdx.x;
  int wave = tid >> 6, lane = tid & 63;
  int quad = lane >> 4, l16 = lane & 15;
  int wm = wave >> 1, wn = wave & 1;
  int mtile = blockIdx.x * 128, ntile = blockIdx.y * 128;
  const u16* Ap = A + (size_t)mtile * 256;
  const u16* Bp = Wt + (size_t)ntile * 256;
  f32x4 acc[4][4];
#pragma unroll
  for (int am = 0; am < 4; am++)
#pragma unroll
    for (int bn = 0; bn < 4; bn++) acc[am][bn] = (f32x4){0.f, 0.f, 0.f, 0.f};
  for (int ks = 0; ks < 4; ks++) {
    __syncthreads();
#pragma unroll
    for (int i = 0; i < 4; i++) {
      int s = i * 256 + tid;
      int r = s >> 3, c = s & 7;
      gl_lds16(Ap + r * 256 + ks * 64 + ((c ^ (r & 7)) << 3), As + s * 8);
    }
#pragma unroll
    for (int i = 0; i < 4; i++) {
      int s = i * 256 + tid;
      int r = s >> 3, c = s & 7;
      gl_lds16(Bp + r * 256 + ks * 64 + ((c ^ (r & 7)) << 3), Bs + s * 8);
    }
    __syncthreads();
#pragma unroll
    for (int kc = 0; kc < 2; kc++) {
      bf16x8 a[4], b[4];
      int cc = kc * 4 + quad;
#pragma unroll
      for (int am = 0; am < 4; am++) {
        int rl = wm * 64 + am * 16 + l16;
        a[am] = *(const bf16x8*)(As + rl * 64 + ((cc ^ (rl & 7)) << 3));
      }
#pragma unroll
      for (int bn = 0; bn < 4; bn++) {
        int rl = wn * 64 + bn * 16 + l16;
        b[bn] = *(const bf16x8*)(Bs + rl * 64 + ((cc ^ (rl & 7)) << 3));
      }
#pragma unroll
      for (int am = 0; am < 4; am++)
#pragma unroll
        for (int bn = 0; bn < 4; bn++)
          acc[am][bn] = __builtin_amdgcn_mfma_f32_16x16x32_bf16(a[am], b[bn], acc[am][bn], 0, 0, 0);
    }
  }
#pragma unroll
  for (int am = 0; am < 4; am++)
#pragma unroll
    for (int bn = 0; bn < 4; bn++)
#pragma unroll
      for (int r = 0; r < 4; r++) {
        int row = mtile + wm * 64 + am * 16 + quad * 4 + r;
        int col = ntile + wn * 64 + bn * 16 + l16;
        KebT[(size_t)(col >> 3) * 65536 + row * 8 + (col & 7)] =
            f2b((acc[am][bn][r] + bias[col]) * C1EXP);
      }
}

// ---------------- flash staging helpers: 32-key tiles (16 KB each), 512 threads ----
__device__ __forceinline__ void stage_k(const u16* __restrict__ KebT, u16* KeL,
                                        int kbase, int tid) {
#pragma unroll
  for (int i = 0; i < 2; i++) {
    int s = i * 512 + tid;
    int c = s >> 5, r = s & 31;
    gl_lds16(KebT + ((size_t)c * 8192 + kbase + r) * 8, KeL + s * 8);
  }
}
__device__ __forceinline__ void stage_v(const u16* __restrict__ XeTc, u16* VLT,
                                        int ktg, int tid) {
  int kb8 = ktg * 4;
#pragma unroll
  for (int i = 0; i < 2; i++) {
    int s = i * 512 + tid;
    int kc = s >> 8, ch = s & 255;
    gl_lds16(XeTc + ((size_t)(kb8 + kc) * 256 + ch) * 8, VLT + s * 8);
  }
}

// ---------------- flash partial: 512-thread blocks, pipelined PV(t-1) || QK(t) ------
// 256 blocks = 64 q-tiles (256 rows) x 4 key-splits; 8 waves each own 32 q-rows;
// 64 iters of 32 keys. ONE block/CU (80 KB LDS): K double-buffered (2x16K),
// V TRIPLE-buffered (3x16K) so V(t-1) survives into iter t. One barrier per iter.
// Inner loop 1:1-interleaves the QK(t) dependent chain with the independent PV(t-1)
// MFMAs -> MFMA + LDS pipes continuously fed; exp/pack VALU tail overlaps the other
// wave's MFMA phase. Buffer indices compile-time via period-6 unroll.
// Registers: o=128 AGPR; VGPR qf(64)+s0(16)+pf(8)+w(8)+temps < 128 -> 2 waves/SIMD.
__global__ __launch_bounds__(512, 2) void k_flash(const u16* __restrict__ QKV,
                                                  const u16* __restrict__ KebT,
                                                  const u16* __restrict__ XeTc,
                                                  u16* __restrict__ Op,
                                                  float* __restrict__ Lv) {
  extern __shared__ u16 sm[];
  // K bufs: sm + KB*8192 (KB=0,1); V bufs: sm + 16384 + VB*8192 (VB=0,1,2). 80 KB.
  int tid = threadIdx.x;
  int wave = tid >> 6, lane = tid & 63;
  int l31 = lane & 31, half = lane >> 5;
  int qt = blockIdx.x & 63;
  int split = blockIdx.x >> 6;
  int rowq = qt * 256 + wave * 32 + l31;

  bf16x8 qf[16];
#pragma unroll
  for (int ks = 0; ks < 16; ks++)
    qf[ks] = *(const bf16x8*)(QKV + (size_t)rowq * 768 + ks * 16 + half * 8);

  f32x16 o[8];
#pragma unroll
  for (int i = 0; i < 8; i++)
#pragma unroll
    for (int r = 0; r < 16; r++) o[i][r] = 0.f;
  float lsum = 0.f;
  bf16x8 pf0 = {}, pf1 = {};

  // prologue: K(0) -> kb0, V(0) -> vb0
  stage_k(KebT, sm, split * 2048, tid);
  stage_v(XeTc, sm + 16384, split * 64, tid);

#define FLASH_STEP(T, KB, VR, VW, DO_STAGE, DO_PV)                                 \
  {                                                                                \
    __syncthreads();                                                               \
    if (DO_STAGE) {                                                                \
      stage_k(KebT, sm + ((KB) ^ 1) * 8192, (split * 64 + (T) + 1) * 32, tid);     \
      stage_v(XeTc, sm + 16384 + (VW) * 8192, split * 64 + (T) + 1, tid);          \
    }                                                                              \
    const u16* kp = sm + (KB) * 8192 + half * 256 + l31 * 8;                       \
    const u16* vp = sm + 16384 + (VR) * 8192 + half * 2048 + l31 * 8;              \
    f32x16 s0;                                                                     \
    _Pragma("unroll") for (int r = 0; r < 16; r++) s0[r] = 0.f;                    \
    __builtin_amdgcn_s_setprio(1);                                                 \
    _Pragma("unroll") for (int j = 0; j < 16; j++) {                               \
      bf16x8 ka = *(const bf16x8*)(kp + j * 512);                                  \
      s0 = __builtin_amdgcn_mfma_f32_32x32x16_bf16(ka, qf[j], s0, 0, 0, 0);        \
      if (DO_PV) {                                                                 \
        bf16x8 vb = *(const bf16x8*)(vp + (j >> 1) * 256 + (j & 1) * 4096);        \
        o[j >> 1] = __builtin_amdgcn_mfma_f32_32x32x16_bf16(                       \
            (j & 1) ? pf1 : pf0, vb, o[j >> 1], 0, 0, 0);                          \
      }                                                                            \
    }                                                                              \
    __builtin_amdgcn_s_setprio(0);                                                 \
    u32 w[8];                                                                      \
    _Pragma("unroll") for (int i = 0; i < 8; i++) {                                \
      float e0 = __builtin_amdgcn_exp2f(s0[2 * i]);                                \
      float e1 = __builtin_amdgcn_exp2f(s0[2 * i + 1]);                            \
      lsum += e0 + e1;                                                             \
      w[i] = cvtpk(e0, e1);                                                        \
    }                                                                              \
    {                                                                              \
      u32x2 r;                                                                     \
      r = swap32v(w[2], w[0]); w[2] = r.x; w[0] = r.y;                             \
      r = swap32v(w[3], w[1]); w[3] = r.x; w[1] = r.y;                             \
      r = swap32v(w[6], w[4]); w[6] = r.x; w[4] = r.y;                             \
      r = swap32v(w[7], w[5]); w[7] = r.x; w[5] = r.y;                             \
    }                                                                              \
    u32x4 p0v = {w[0], w[1], w[2], w[3]};                                          \
    u32x4 p1v = {w[4], w[5], w[6], w[7]};                                          \
    pf0 = __builtin_bit_cast(bf16x8, p0v);                                         \
    pf1 = __builtin_bit_cast(bf16x8, p1v);                                         \
  }

  // t=0: stage t=1 -> kb1/vb1; QK only (no PV yet)
  FLASH_STEP(0, 0, 0, 1, 1, 0);
  // t = 1..60 (period-6 buffer pattern: KB=T&1, VR=(T-1)%3, VW=(T+1)%3)
  for (int tb = 1; tb < 61; tb += 6) {
    FLASH_STEP(tb + 0, 1, 0, 2, 1, 1);
    FLASH_STEP(tb + 1, 0, 1, 0, 1, 1);
    FLASH_STEP(tb + 2, 1, 2, 1, 1, 1);
    FLASH_STEP(tb + 3, 0, 0, 2, 1, 1);
    FLASH_STEP(tb + 4, 1, 1, 0, 1, 1);
    FLASH_STEP(tb + 5, 0, 2, 1, 1, 1);
  }
  FLASH_STEP(61, 1, 0, 2, 1, 1);
  FLASH_STEP(62, 0, 1, 0, 1, 1);
  FLASH_STEP(63, 1, 2, 0, 0, 1);
#undef FLASH_STEP

  // epilogue: PV(63) from vb0 (staged during t=62, confirmed by barrier at t=63)
  {
    const u16* vp = sm + 16384 + half * 2048 + l31 * 8;
    __builtin_amdgcn_s_setprio(1);
#pragma unroll
    for (int j = 0; j < 16; j++) {
      bf16x8 vb = *(const bf16x8*)(vp + (j >> 1) * 256 + (j & 1) * 4096);
      o[j >> 1] = __builtin_amdgcn_mfma_f32_32x32x16_bf16(
          (j & 1) ? pf1 : pf0, vb, o[j >> 1], 0, 0, 0);
    }
    __builtin_amdgcn_s_setprio(0);
  }

  // per-lane scalar holds the partial row-sum for q = l31 over this lane's keys
  lsum += __shfl_xor(lsum, 32, 64);
  if (lane < 32) Lv[split * N_NODES + qt * 256 + wave * 32 + l31] = lsum;

  size_t obase = (size_t)split * N_NODES * 256;
#pragma unroll
  for (int ct = 0; ct < 8; ct++)
#pragma unroll
    for (int reg = 0; reg < 16; reg++) {
      int row = qt * 256 + wave * 32 + (reg & 3) + 8 * (reg >> 2) + 4 * half;
      int col = ct * 32 + l31;
      Op[obase + (size_t)row * 256 + col] = f2b(o[ct][reg]);
    }
}

// ---------------- fused: node 8x8 head attention + split combine + ReLU ----------------
__global__ __launch_bounds__(256) void k_comb(const u16* __restrict__ QKV,
                                              const u16* __restrict__ Op,
                                              const float* __restrict__ Lv,
                                              float* __restrict__ out) {
  int idx = blockIdx.x * 256 + threadIdx.x;
  int n = idx >> 6, lane = idx & 63;
  int h = lane >> 3, g = lane & 7;
  const u16* base = QKV + n * 768;
  const bf16x8* qp = (const bf16x8*)(base + h * 32);
  const bf16x8* kp = (const bf16x8*)(base + 256 + g * 32);
  float s = 0.f;
#pragma unroll
  for (int t = 0; t < 4; t++) {
    bf16x8 qv = qp[t], kv = kp[t];
#pragma unroll
    for (int j = 0; j < 8; j++) s += b2f((u16)qv[j]) * b2f((u16)kv[j]);
  }
  s *= FK_SCALE;
  float mx = s;
#pragma unroll
  for (int off = 1; off < 8; off <<= 1) mx = fmaxf(mx, __shfl_xor(mx, off, 64));
  float p = __builtin_amdgcn_exp2f((s - mx) * LOG2E);
  float lsum = p;
#pragma unroll
  for (int off = 1; off < 8; off <<= 1) lsum += __shfl_xor(lsum, off, 64);
  float attn = p / lsum;
  float a4[4] = {0.f, 0.f, 0.f, 0.f};
#pragma unroll
  for (int g2 = 0; g2 < 8; g2++) {
    float a = __shfl(attn, (lane & 56) | g2, 64);
    bf16x4 vv = *(const bf16x4*)(base + 512 + g2 * 32 + g * 4);
#pragma unroll
    for (int j = 0; j < 4; j++) a4[j] += a * b2f((u16)vv[j]);
  }
  int c4 = lane * 4;
  float L = 0.f;
#pragma unroll
  for (int sl = 0; sl < 4; sl++) L += Lv[sl * N_NODES + n];
  f32x4 acc = {0.f, 0.f, 0.f, 0.f};
#pragma unroll
  for (int sp = 0; sp < 4; sp++) {
    u16x4 ov = *(const u16x4*)(Op + (size_t)sp * N_NODES * 256 + (size_t)n * 256 + c4);
    acc.x += b2f(ov.x);
    acc.y += b2f(ov.y);
    acc.z += b2f(ov.z);
    acc.w += b2f(ov.w);
  }
  float invL = 1.0f / L;
  f32x4 res;
  res.x = fmaxf(acc.x * invL + a4[0], 0.f);
  res.y = fmaxf(acc.y * invL + a4[1], 0.f);
  res.z = fmaxf(acc.z * invL + a4[2], 0.f);
  res.w = fmaxf(acc.w * invL + a4[3], 0.f);
  *(f32x4*)(out + (size_t)n * 256 + c4) = res;
}

extern "C" void kernel_launch(void* const* d_in, const int* in_sizes, int n_in,
                              void* d_out, int out_size, void* d_ws, size_t ws_size,
                              hipStream_t stream) {
  const float* X = (const float*)d_in[0];
  const int* v_ids = (const int*)d_in[1];
  const int* e_ids = (const int*)d_in[2];
  const float* Wq = (const float*)d_in[3];
  const float* bq = (const float*)d_in[4];
  const float* Wk = (const float*)d_in[5];
  const float* bk = (const float*)d_in[6];
  const float* Wv = (const float*)d_in[7];
  const float* bv = (const float*)d_in[8];
  const float* Wke = (const float*)d_in[9];
  const float* bke = (const float*)d_in[10];
  float* out = (float*)d_out;

  char* ws = (char*)d_ws;
  u16* Xb = (u16*)(ws);                       // 8 MB   [N][256] bf16
  u16* QKV = (u16*)(ws + 8388608);            // 24 MB  [N][768] bf16
  u16* Wt = (u16*)(ws + 33554432);            // 512 KB
  float* bcat = (float*)(ws + 34078720);      // 4 KB
  int* hist = (int*)(ws + 34082816);          // 32 KB
  int* eoff = (int*)(ws + 34115584);          // 36 KB
  int* cur = (int*)(ws + 34152448);           // 32 KB
  int* perm = (int*)(ws + 34185216);          // 1 MB
  u16* Xe = (u16*)(ws + 35233792);            // 4 MB   [E][256]
  u16* XeTc = (u16*)(ws + 39428096);          // 4 MB   [E/8][256][8]
  u16* KebT = (u16*)(ws + 43622400);          // 4 MB   [32][E][8] (pre-scaled C1EXP)
  u16* Op = (u16*)(ws + 64593920);            // 32 MB  [4][N][256] bf16
  float* Lv = (float*)(ws + 98148352);        // 256 KB [4][N]

  hipMemsetAsync(hist, 0, 32768, stream);
  k_prep<<<4160, 256, 0, stream>>>(X, e_ids, Xb, hist, Wq, Wk, Wv, Wke,
                                   bq, bk, bv, bke, Wt, bcat);
  k_scan<<<1, 256, 0, stream>>>(hist, eoff, cur);
  k_perm<<<256, 256, 0, stream>>>(v_ids, e_ids, cur, perm);
  k_gg<<<2816, 256, 0, stream>>>(Xb, perm, eoff, Xe, XeTc, Wt, bcat, QKV);
  k_gemmke<<<dim3(64, 2), 256, 0, stream>>>(Xe, Wt + 3 * 65536, bcat + 768, KebT);
  hipFuncSetAttribute((const void*)k_flash, hipFuncAttributeMaxDynamicSharedMemorySize,
                      81920);
  k_flash<<<256, 512, 81920, stream>>>(QKV, KebT, XeTc, Op, Lv);
  k_comb<<<4096, 256, 0, stream>>>(QKV, Op, Lv, out);
}